// Round 1
// baseline (983.105 us; speedup 1.0000x reference)
//
#include <hip/hip_runtime.h>
#include <math.h>

// Problem constants
#define Bc   4
#define Hc   64
#define Wc   64
#define Dc   384
#define Nc   4096      // H*W
#define Mc   12
#define Pc   9
#define DHc  32
#define DFFc 1152
#define BNc  (Bc*Nc)   // 16384

// ---------------------------------------------------------------------------
// K0: cumsum of not_mask along H (cum_y) and W (cum_x)
// ---------------------------------------------------------------------------
__global__ void cumsum_mask_kernel(const float* __restrict__ qmask,
                                   float* __restrict__ cum_y,
                                   float* __restrict__ cum_x) {
    int t = blockIdx.x * blockDim.x + threadIdx.x;
    if (t < Bc * Wc) {
        int b = t / Wc, w = t % Wc;
        float run = 0.f;
        for (int h = 0; h < Hc; ++h) {
            float nm = (qmask[(b * Hc + h) * Wc + w] == 255.0f) ? 0.f : 1.f;
            run += nm;
            cum_y[(b * Hc + h) * Wc + w] = run;
        }
    } else if (t < Bc * Wc + Bc * Hc) {
        int t2 = t - Bc * Wc;
        int b = t2 / Hc, h = t2 % Hc;
        float run = 0.f;
        for (int w = 0; w < Wc; ++w) {
            float nm = (qmask[(b * Hc + h) * Wc + w] == 255.0f) ? 0.f : 1.f;
            run += nm;
            cum_x[(b * Hc + h) * Wc + w] = run;
        }
    }
}

// ---------------------------------------------------------------------------
// K1: transpose x[B,D,N] -> src[B,N,D]; qpos = src + sine_pos + level_embed
// ---------------------------------------------------------------------------
__global__ void transpose_pos_kernel(const float* __restrict__ x,
                                     const float* __restrict__ cum_y,
                                     const float* __restrict__ cum_x,
                                     const float* __restrict__ level_embed,
                                     float* __restrict__ src,
                                     float* __restrict__ qpos) {
    __shared__ float tile[32][33];
    int b  = blockIdx.z;
    int n0 = blockIdx.x * 32, d0 = blockIdx.y * 32;
    int tx = threadIdx.x, ty = threadIdx.y;
    // coalesced read along n
    tile[ty][tx] = x[((size_t)b * Dc + (d0 + ty)) * Nc + (n0 + tx)];
    __syncthreads();
    int n = n0 + ty, d = d0 + tx;
    float v = tile[tx][ty];
    size_t oi = ((size_t)b * Nc + n) * Dc + d;
    src[oi] = v;
    int h = n >> 6, w = n & 63;
    const float TWO_PI = 6.28318530717958647692f;
    float vy = cum_y[(b * Hc + h) * Wc + w] /
               (cum_y[(b * Hc + (Hc - 1)) * Wc + w] + 1e-6f) * TWO_PI;
    float vx = cum_x[(b * Hc + h) * Wc + w] /
               (cum_x[(b * Hc + h) * Wc + (Wc - 1)] + 1e-6f) * TWO_PI;
    int   i  = (d < 192) ? d : d - 192;
    float vv = (d < 192) ? vy : vx;
    float dt  = powf(10000.0f, (float)(i >> 1) * (2.0f / 192.0f));
    float ang = vv / dt;
    float pe  = (i & 1) ? cosf(ang) : sinf(ang);
    qpos[oi] = v + pe + level_embed[d];
}

// ---------------------------------------------------------------------------
// K2: generic tiled fp32 GEMM  C[M,N] = A[M,K] * Wt[N,K]^T (+bias) (+relu)
//     optional row-masking (value projection: mask rows -> 0)
//     Requires: Mrows % 64 == 0, K % 16 == 0. N arbitrary (guarded).
// ---------------------------------------------------------------------------
__global__ __launch_bounds__(256) void gemm_kernel(
        const float* __restrict__ A, const float* __restrict__ Wt,
        const float* __restrict__ bias, float* __restrict__ C,
        int Nout, int K, int relu, const float* __restrict__ qmask) {
    __shared__ float As[16][68];
    __shared__ float Bs[16][68];
    int m0  = blockIdx.y * 64;
    int nb0 = blockIdx.x * 64;
    int tid = threadIdx.y * 16 + threadIdx.x;
    int lr  = tid >> 2;        // 0..63
    int lk  = (tid & 3) * 4;   // 0,4,8,12

    float acc[4][4] = {{0.f}};

    for (int k0 = 0; k0 < K; k0 += 16) {
        float4 av = *(const float4*)(A + (size_t)(m0 + lr) * K + k0 + lk);
        As[lk + 0][lr] = av.x; As[lk + 1][lr] = av.y;
        As[lk + 2][lr] = av.z; As[lk + 3][lr] = av.w;
        int wr = nb0 + lr;
        float4 bv = make_float4(0.f, 0.f, 0.f, 0.f);
        if (wr < Nout) bv = *(const float4*)(Wt + (size_t)wr * K + k0 + lk);
        Bs[lk + 0][lr] = bv.x; Bs[lk + 1][lr] = bv.y;
        Bs[lk + 2][lr] = bv.z; Bs[lk + 3][lr] = bv.w;
        __syncthreads();
        #pragma unroll
        for (int kk = 0; kk < 16; ++kk) {
            float4 a4 = *(const float4*)&As[kk][threadIdx.y * 4];
            float4 b4 = *(const float4*)&Bs[kk][threadIdx.x * 4];
            float a[4]  = {a4.x, a4.y, a4.z, a4.w};
            float bb[4] = {b4.x, b4.y, b4.z, b4.w};
            #pragma unroll
            for (int i2 = 0; i2 < 4; ++i2)
                #pragma unroll
                for (int j = 0; j < 4; ++j)
                    acc[i2][j] += a[i2] * bb[j];
        }
        __syncthreads();
    }

    #pragma unroll
    for (int i2 = 0; i2 < 4; ++i2) {
        int row = m0 + threadIdx.y * 4 + i2;
        float mz = 1.f;
        if (qmask && qmask[row] == 255.0f) mz = 0.f;
        #pragma unroll
        for (int j = 0; j < 4; ++j) {
            int col = nb0 + threadIdx.x * 4 + j;
            if (col < Nout) {
                float v2 = acc[i2][j] + (bias ? bias[col] : 0.f);
                if (relu) v2 = fmaxf(v2, 0.f);
                C[(size_t)row * Nout + col] = v2 * mz;
            }
        }
    }
}

// ---------------------------------------------------------------------------
// K3: softmax over P=9 per (b,n,m), in place
// ---------------------------------------------------------------------------
__global__ void softmax_p_kernel(float* __restrict__ aw) {
    int idx = blockIdx.x * 256 + threadIdx.x;
    if (idx >= BNc * Mc) return;
    float* p = aw + (size_t)idx * Pc;
    float mx = p[0];
    #pragma unroll
    for (int i = 1; i < Pc; ++i) mx = fmaxf(mx, p[i]);
    float e[Pc];
    float s = 0.f;
    #pragma unroll
    for (int i = 0; i < Pc; ++i) { e[i] = expf(p[i] - mx); s += e[i]; }
    float inv = 1.f / s;
    #pragma unroll
    for (int i = 0; i < Pc; ++i) p[i] = e[i] * inv;
}

// ---------------------------------------------------------------------------
// K4: deformable attention gather.
//     One 32-lane group per (b,n,m); lane = dh. Coalesced 128B value reads.
// ---------------------------------------------------------------------------
__global__ __launch_bounds__(256) void deform_attn_kernel(
        const float* __restrict__ value, const float* __restrict__ so,
        const float* __restrict__ aw, float* __restrict__ out) {
    int gid  = blockIdx.x * 8 + (threadIdx.x >> 5);   // (b*N+n)*M + m
    int lane = threadIdx.x & 31;                       // dh
    int m  = gid % Mc;
    int bn = gid / Mc;
    int b  = bn >> 12;         // N = 4096
    int n  = bn & 4095;
    int h  = n >> 6, w = n & 63;
    float refx = (w + 0.5f) * (1.0f / 64.0f);
    float refy = (h + 0.5f) * (1.0f / 64.0f);
    const float* sop = so + (size_t)bn * (Mc * Pc * 2) + m * (Pc * 2);
    const float* awp = aw + (size_t)bn * (Mc * Pc) + m * Pc;
    const float* vb  = value + ((size_t)b * Nc) * Dc + m * DHc + lane;
    float acc = 0.f;
    #pragma unroll
    for (int p = 0; p < Pc; ++p) {
        float px = (refx + sop[p * 2 + 0] * (1.0f / 64.0f)) * 64.0f - 0.5f;
        float py = (refy + sop[p * 2 + 1] * (1.0f / 64.0f)) * 64.0f - 0.5f;
        float x0f = floorf(px), y0f = floorf(py);
        float lx = px - x0f, ly = py - y0f;
        int x0 = (int)x0f, y0 = (int)y0f;
        float a = awp[p];
        float wgt[4] = {(1.f - lx) * (1.f - ly), lx * (1.f - ly),
                        (1.f - lx) * ly,         lx * ly};
        const int dxs[4] = {0, 1, 0, 1};
        const int dys[4] = {0, 0, 1, 1};
        float s = 0.f;
        #pragma unroll
        for (int c2 = 0; c2 < 4; ++c2) {
            int xi = x0 + dxs[c2], yi = y0 + dys[c2];
            if (xi >= 0 && xi < Wc && yi >= 0 && yi < Hc)
                s += wgt[c2] * vb[(size_t)(yi * Wc + xi) * Dc];
        }
        acc += a * s;
    }
    out[(size_t)bn * Dc + m * DHc + lane] = acc;
}

// ---------------------------------------------------------------------------
// K5: out = LayerNorm(a + r) * g + beta   (row of 384, block of 128 threads)
// ---------------------------------------------------------------------------
__global__ __launch_bounds__(128) void ln_residual_kernel(
        const float* __restrict__ a, const float* __restrict__ r,
        const float* __restrict__ g, const float* __restrict__ beta,
        float* __restrict__ out) {
    int row = blockIdx.x;
    int tid = threadIdx.x;
    float v[3];
    float s1 = 0.f, s2 = 0.f;
    #pragma unroll
    for (int i = 0; i < 3; ++i) {
        int d = i * 128 + tid;
        float t = a[(size_t)row * Dc + d] + r[(size_t)row * Dc + d];
        v[i] = t; s1 += t; s2 += t * t;
    }
    __shared__ float sh1[128], sh2[128];
    sh1[tid] = s1; sh2[tid] = s2;
    __syncthreads();
    for (int off = 64; off > 0; off >>= 1) {
        if (tid < off) { sh1[tid] += sh1[tid + off]; sh2[tid] += sh2[tid + off]; }
        __syncthreads();
    }
    float mu  = sh1[0] * (1.0f / Dc);
    float var = sh2[0] * (1.0f / Dc) - mu * mu;
    float rs  = rsqrtf(var + 1e-5f);
    #pragma unroll
    for (int i = 0; i < 3; ++i) {
        int d = i * 128 + tid;
        out[(size_t)row * Dc + d] = (v[i] - mu) * rs * g[d] + beta[d];
    }
}

// ---------------------------------------------------------------------------
// K6: transpose src[B,N,D] -> out[B,D,N]
// ---------------------------------------------------------------------------
__global__ void transpose_out_kernel(const float* __restrict__ src,
                                     float* __restrict__ out) {
    __shared__ float tile[32][33];
    int b  = blockIdx.z;
    int n0 = blockIdx.x * 32, d0 = blockIdx.y * 32;
    int tx = threadIdx.x, ty = threadIdx.y;
    tile[ty][tx] = src[((size_t)b * Nc + (n0 + ty)) * Dc + (d0 + tx)];
    __syncthreads();
    out[((size_t)b * Dc + (d0 + ty)) * Nc + (n0 + tx)] = tile[tx][ty];
}

// ---------------------------------------------------------------------------
extern "C" void kernel_launch(void* const* d_in, const int* in_sizes, int n_in,
                              void* d_out, int out_size, void* d_ws, size_t ws_size,
                              hipStream_t stream) {
    (void)in_sizes; (void)n_in; (void)out_size; (void)ws_size;
    const float* x      = (const float*)d_in[0];
    const float* qmask  = (const float*)d_in[1];
    const float* so_w   = (const float*)d_in[2];
    const float* so_b   = (const float*)d_in[3];
    const float* aw_w   = (const float*)d_in[4];
    const float* aw_b   = (const float*)d_in[5];
    const float* vp_w   = (const float*)d_in[6];
    const float* vp_b   = (const float*)d_in[7];
    const float* op_w   = (const float*)d_in[8];
    const float* op_b   = (const float*)d_in[9];
    const float* ln1_g  = (const float*)d_in[10];
    const float* ln1_b  = (const float*)d_in[11];
    const float* w1     = (const float*)d_in[12];
    const float* w2     = (const float*)d_in[13];
    const float* ln2_g  = (const float*)d_in[14];
    const float* ln2_b  = (const float*)d_in[15];
    const float* lvl    = (const float*)d_in[16];
    float* out = (float*)d_out;

    // Workspace layout (floats). so/aw/dbuf alias hbuf: they are dead before
    // FFN1 overwrites hbuf.  Total: 3*6291456 + 18874368 + 2*16384 = 37,814,272
    // floats = 151.3 MB.
    float* ws    = (float*)d_ws;
    float* src   = ws;                    // [B,N,D], also final q2
    float* qpos  = src  + 6291456;        // q+pos; later attn_mid; later q1
    float* value = qpos + 6291456;        // projected value; later FFN2 out
    float* hbuf  = value + 6291456;       // [BN,1152] FFN hidden
    float* so    = hbuf;                  // [BN,216]  (aliases hbuf, dead by FFN1)
    float* aw    = hbuf + 3538944;        // [BN,108]
    float* dbuf  = hbuf + 5308416;        // [BN,384] op-proj out
    float* cum_y = hbuf + 18874368;
    float* cum_x = cum_y + 16384;

    // 0) mask cumsums
    cumsum_mask_kernel<<<2, 256, 0, stream>>>(qmask, cum_y, cum_x);
    // 1) src + qpos
    transpose_pos_kernel<<<dim3(Nc / 32, Dc / 32, Bc), dim3(32, 32), 0, stream>>>(
        x, cum_y, cum_x, lvl, src, qpos);
    // 2) sampling offsets / attention weights / value projection
    gemm_kernel<<<dim3(4, BNc / 64), dim3(16, 16), 0, stream>>>(
        qpos, so_w, so_b, so, 216, Dc, 0, nullptr);
    gemm_kernel<<<dim3(2, BNc / 64), dim3(16, 16), 0, stream>>>(
        qpos, aw_w, aw_b, aw, 108, Dc, 0, nullptr);
    gemm_kernel<<<dim3(6, BNc / 64), dim3(16, 16), 0, stream>>>(
        src, vp_w, vp_b, value, Dc, Dc, 0, qmask);
    // 3) softmax over P
    softmax_p_kernel<<<(BNc * Mc) / 256, 256, 0, stream>>>(aw);
    // 4) deformable gather -> attn_mid (in qpos)
    deform_attn_kernel<<<(BNc * Mc) / 8, 256, 0, stream>>>(value, so, aw, qpos);
    // 5) output projection
    gemm_kernel<<<dim3(6, BNc / 64), dim3(16, 16), 0, stream>>>(
        qpos, op_w, op_b, dbuf, Dc, Dc, 0, nullptr);
    // 6) q1 = LN(src + attn)
    ln_residual_kernel<<<BNc, 128, 0, stream>>>(src, dbuf, ln1_g, ln1_b, qpos);
    // 7) FFN
    gemm_kernel<<<dim3(18, BNc / 64), dim3(16, 16), 0, stream>>>(
        qpos, w1, nullptr, hbuf, DFFc, Dc, 1, nullptr);
    gemm_kernel<<<dim3(6, BNc / 64), dim3(16, 16), 0, stream>>>(
        hbuf, w2, nullptr, value, Dc, DFFc, 0, nullptr);
    // 8) q2 = LN(q1 + ffn) -> src
    ln_residual_kernel<<<BNc, 128, 0, stream>>>(qpos, value, ln2_g, ln2_b, src);
    // 9) transpose to [B,D,H,W]
    transpose_out_kernel<<<dim3(Nc / 32, Dc / 32, Bc), dim3(32, 32), 0, stream>>>(
        src, out);
}

// Round 2
// 530.856 us; speedup vs baseline: 1.8519x; 1.8519x over previous
//
#include <hip/hip_runtime.h>
#include <math.h>

// Problem constants
#define Bc   4
#define Hc   64
#define Wc   64
#define Dc   384
#define Nc   4096      // H*W
#define Mc   12
#define Pc   9
#define DHc  32
#define DFFc 1152
#define BNc  (Bc*Nc)   // 16384

typedef __attribute__((ext_vector_type(8))) short short8;
typedef __attribute__((ext_vector_type(4))) float floatx4;

__device__ __forceinline__ ushort f2bf(float f) {
    union { float f; unsigned u; } v; v.f = f;
    unsigned r = v.u + 0x7fffu + ((v.u >> 16) & 1u);   // RNE
    return (ushort)(r >> 16);
}

// ---------------------------------------------------------------------------
// K0: cumsum of not_mask along H (cum_y) and W (cum_x)
// ---------------------------------------------------------------------------
__global__ void cumsum_mask_kernel(const float* __restrict__ qmask,
                                   float* __restrict__ cum_y,
                                   float* __restrict__ cum_x) {
    int t = blockIdx.x * blockDim.x + threadIdx.x;
    if (t < Bc * Wc) {
        int b = t / Wc, w = t % Wc;
        float run = 0.f;
        for (int h = 0; h < Hc; ++h) {
            float nm = (qmask[(b * Hc + h) * Wc + w] == 255.0f) ? 0.f : 1.f;
            run += nm;
            cum_y[(b * Hc + h) * Wc + w] = run;
        }
    } else if (t < Bc * Wc + Bc * Hc) {
        int t2 = t - Bc * Wc;
        int b = t2 / Hc, h = t2 % Hc;
        float run = 0.f;
        for (int w = 0; w < Wc; ++w) {
            float nm = (qmask[(b * Hc + h) * Wc + w] == 255.0f) ? 0.f : 1.f;
            run += nm;
            cum_x[(b * Hc + h) * Wc + w] = run;
        }
    }
}

// ---------------------------------------------------------------------------
// K1: transpose x[B,D,N] -> src_f[B,N,D] (fp32) + src_bf (bf16);
//     qpos_bf = bf16(src + sine_pos + level_embed)
// ---------------------------------------------------------------------------
__global__ void transpose_pos_kernel(const float* __restrict__ x,
                                     const float* __restrict__ cum_y,
                                     const float* __restrict__ cum_x,
                                     const float* __restrict__ level_embed,
                                     float* __restrict__ src_f,
                                     ushort* __restrict__ src_bf,
                                     ushort* __restrict__ qpos_bf) {
    __shared__ float tile[32][33];
    int b  = blockIdx.z;
    int n0 = blockIdx.x * 32, d0 = blockIdx.y * 32;
    int tx = threadIdx.x, ty = threadIdx.y;
    tile[ty][tx] = x[((size_t)b * Dc + (d0 + ty)) * Nc + (n0 + tx)];
    __syncthreads();
    int n = n0 + ty, d = d0 + tx;
    float v = tile[tx][ty];
    size_t oi = ((size_t)b * Nc + n) * Dc + d;
    src_f[oi]  = v;
    src_bf[oi] = f2bf(v);
    int h = n >> 6, w = n & 63;
    const float TWO_PI = 6.28318530717958647692f;
    float vy = cum_y[(b * Hc + h) * Wc + w] /
               (cum_y[(b * Hc + (Hc - 1)) * Wc + w] + 1e-6f) * TWO_PI;
    float vx = cum_x[(b * Hc + h) * Wc + w] /
               (cum_x[(b * Hc + h) * Wc + (Wc - 1)] + 1e-6f) * TWO_PI;
    int   i  = (d < 192) ? d : d - 192;
    float vv = (d < 192) ? vy : vx;
    float dt  = powf(10000.0f, (float)(i >> 1) * (2.0f / 192.0f));
    float ang = vv / dt;
    float pe  = (i & 1) ? cosf(ang) : sinf(ang);
    qpos_bf[oi] = f2bf(v + pe + level_embed[d]);
}

// ---------------------------------------------------------------------------
// K1b: convert all six weight matrices fp32 -> bf16 into wbuf
// ---------------------------------------------------------------------------
#define SOW_N  82944     // 216*384
#define AWW_N  41472     // 108*384
#define VPW_N  147456    // 384*384
#define OPW_N  147456
#define W1_N   442368    // 1152*384
#define W2_N   442368    // 384*1152
#define WTOT   1304064

__global__ void convert_weights_kernel(const float* __restrict__ so_w,
                                       const float* __restrict__ aw_w,
                                       const float* __restrict__ vp_w,
                                       const float* __restrict__ op_w,
                                       const float* __restrict__ w1,
                                       const float* __restrict__ w2,
                                       ushort* __restrict__ out) {
    int i = blockIdx.x * 256 + threadIdx.x;
    if (i >= WTOT) return;
    float v;
    int j = i;
    if (j < SOW_N) v = so_w[j];
    else if ((j -= SOW_N) < AWW_N) v = aw_w[j];
    else if ((j -= AWW_N) < VPW_N) v = vp_w[j];
    else if ((j -= VPW_N) < OPW_N) v = op_w[j];
    else if ((j -= OPW_N) < W1_N)  v = w1[j];
    else { j -= W1_N; v = w2[j]; }
    out[i] = f2bf(v);
}

// ---------------------------------------------------------------------------
// K2: bf16 MFMA GEMM  C[16384,Nout] = A[16384,K](bf16) * Wt[Nout,K](bf16)^T
//     128x128 block tile, 4 waves, each wave 64x64 via 4x4 mfma_16x16x32.
//     Optional: +bias, relu, row-mask (qmask==255 -> 0), fp32 and/or bf16 out.
// ---------------------------------------------------------------------------
__global__ __launch_bounds__(256) void gemm_bf16_kernel(
        const ushort* __restrict__ A, const ushort* __restrict__ Wt,
        const float* __restrict__ bias,
        float* __restrict__ Cf, ushort* __restrict__ Cb,
        int Nout, int K, int relu, const float* __restrict__ qmask) {
    __shared__ ushort As[128 * 40];
    __shared__ ushort Bs[128 * 40];
    const int tid  = threadIdx.x;
    const int m0   = blockIdx.y * 128;
    const int n0   = blockIdx.x * 128;
    const int lane = tid & 63;
    const int wv   = tid >> 6;
    const int wr   = (wv >> 1) * 64;   // wave row offset in tile
    const int wc   = (wv & 1) * 64;    // wave col offset in tile
    const int quad = lane >> 4;
    const int lrow = lane & 15;

    floatx4 acc[4][4];
    #pragma unroll
    for (int i = 0; i < 4; ++i)
        #pragma unroll
        for (int j = 0; j < 4; ++j)
            acc[i][j] = (floatx4)(0.f);

    for (int k0 = 0; k0 < K; k0 += 32) {
        #pragma unroll
        for (int s = 0; s < 2; ++s) {
            int seg = tid + s * 256;        // 0..511
            int row = seg >> 2;
            int c   = (seg & 3) * 8;
            short8 av = *(const short8*)(A + (size_t)(m0 + row) * K + k0 + c);
            *(short8*)(&As[row * 40 + c]) = av;
            int nr = n0 + row;
            short8 bv = (short8)(0);
            if (nr < Nout) bv = *(const short8*)(Wt + (size_t)nr * K + k0 + c);
            *(short8*)(&Bs[row * 40 + c]) = bv;
        }
        __syncthreads();
        short8 afr[4], bfr[4];
        #pragma unroll
        for (int i = 0; i < 4; ++i)
            afr[i] = *(const short8*)(&As[(wr + i * 16 + lrow) * 40 + quad * 8]);
        #pragma unroll
        for (int j = 0; j < 4; ++j)
            bfr[j] = *(const short8*)(&Bs[(wc + j * 16 + lrow) * 40 + quad * 8]);
        #pragma unroll
        for (int i = 0; i < 4; ++i)
            #pragma unroll
            for (int j = 0; j < 4; ++j)
                acc[i][j] = __builtin_amdgcn_mfma_f32_16x16x32_bf16(
                    afr[i], bfr[j], acc[i][j], 0, 0, 0);
        __syncthreads();
    }

    // C/D layout (16x16x32): col = lane&15, row = quad*4 + reg
    #pragma unroll
    for (int i = 0; i < 4; ++i) {
        #pragma unroll
        for (int j = 0; j < 4; ++j) {
            int col = n0 + wc + j * 16 + lrow;
            if (col >= Nout) continue;
            float bsv = bias ? bias[col] : 0.f;
            #pragma unroll
            for (int r = 0; r < 4; ++r) {
                int row = m0 + wr + i * 16 + quad * 4 + r;
                float v = acc[i][j][r] + bsv;
                if (relu) v = fmaxf(v, 0.f);
                if (qmask && qmask[row] == 255.0f) v = 0.f;
                if (Cf) Cf[(size_t)row * Nout + col] = v;
                if (Cb) Cb[(size_t)row * Nout + col] = f2bf(v);
            }
        }
    }
}

// ---------------------------------------------------------------------------
// K3: softmax over P=9 per (b,n,m), in place
// ---------------------------------------------------------------------------
__global__ void softmax_p_kernel(float* __restrict__ aw) {
    int idx = blockIdx.x * 256 + threadIdx.x;
    if (idx >= BNc * Mc) return;
    float* p = aw + (size_t)idx * Pc;
    float mx = p[0];
    #pragma unroll
    for (int i = 1; i < Pc; ++i) mx = fmaxf(mx, p[i]);
    float e[Pc];
    float s = 0.f;
    #pragma unroll
    for (int i = 0; i < Pc; ++i) { e[i] = expf(p[i] - mx); s += e[i]; }
    float inv = 1.f / s;
    #pragma unroll
    for (int i = 0; i < Pc; ++i) p[i] = e[i] * inv;
}

// ---------------------------------------------------------------------------
// K4: deformable attention gather -> bf16 out (feeds op-proj GEMM)
// ---------------------------------------------------------------------------
__global__ __launch_bounds__(256) void deform_attn_kernel(
        const float* __restrict__ value, const float* __restrict__ so,
        const float* __restrict__ aw, ushort* __restrict__ out) {
    int gid  = blockIdx.x * 8 + (threadIdx.x >> 5);   // (b*N+n)*M + m
    int lane = threadIdx.x & 31;                       // dh
    int m  = gid % Mc;
    int bn = gid / Mc;
    int b  = bn >> 12;
    int n  = bn & 4095;
    int h  = n >> 6, w = n & 63;
    float refx = (w + 0.5f) * (1.0f / 64.0f);
    float refy = (h + 0.5f) * (1.0f / 64.0f);
    const float* sop = so + (size_t)bn * (Mc * Pc * 2) + m * (Pc * 2);
    const float* awp = aw + (size_t)bn * (Mc * Pc) + m * Pc;
    const float* vb  = value + ((size_t)b * Nc) * Dc + m * DHc + lane;
    float acc = 0.f;
    #pragma unroll
    for (int p = 0; p < Pc; ++p) {
        float px = (refx + sop[p * 2 + 0] * (1.0f / 64.0f)) * 64.0f - 0.5f;
        float py = (refy + sop[p * 2 + 1] * (1.0f / 64.0f)) * 64.0f - 0.5f;
        float x0f = floorf(px), y0f = floorf(py);
        float lx = px - x0f, ly = py - y0f;
        int x0 = (int)x0f, y0 = (int)y0f;
        float a = awp[p];
        float wgt[4] = {(1.f - lx) * (1.f - ly), lx * (1.f - ly),
                        (1.f - lx) * ly,         lx * ly};
        const int dxs[4] = {0, 1, 0, 1};
        const int dys[4] = {0, 0, 1, 1};
        float s = 0.f;
        #pragma unroll
        for (int c2 = 0; c2 < 4; ++c2) {
            int xi = x0 + dxs[c2], yi = y0 + dys[c2];
            if (xi >= 0 && xi < Wc && yi >= 0 && yi < Hc)
                s += wgt[c2] * vb[(size_t)(yi * Wc + xi) * Dc];
        }
        acc += a * s;
    }
    out[(size_t)bn * Dc + m * DHc + lane] = f2bf(acc);
}

// ---------------------------------------------------------------------------
// K5: out = LayerNorm(a + r) * g + beta ; optional bf16 copy. In-place safe
//     (a == out allowed): all reads of the row happen before any write.
// ---------------------------------------------------------------------------
__global__ __launch_bounds__(128) void ln_residual_kernel(
        const float* a, const float* r,
        const float* g, const float* beta,
        float* out, ushort* outb) {
    int row = blockIdx.x;
    int tid = threadIdx.x;
    float v[3];
    float s1 = 0.f, s2 = 0.f;
    #pragma unroll
    for (int i = 0; i < 3; ++i) {
        int d = i * 128 + tid;
        float t = a[(size_t)row * Dc + d] + r[(size_t)row * Dc + d];
        v[i] = t; s1 += t; s2 += t * t;
    }
    __shared__ float sh1[128], sh2[128];
    sh1[tid] = s1; sh2[tid] = s2;
    __syncthreads();
    for (int off = 64; off > 0; off >>= 1) {
        if (tid < off) { sh1[tid] += sh1[tid + off]; sh2[tid] += sh2[tid + off]; }
        __syncthreads();
    }
    float mu  = sh1[0] * (1.0f / Dc);
    float var = sh2[0] * (1.0f / Dc) - mu * mu;
    float rs  = rsqrtf(var + 1e-5f);
    #pragma unroll
    for (int i = 0; i < 3; ++i) {
        int d = i * 128 + tid;
        float o = (v[i] - mu) * rs * g[d] + beta[d];
        out[(size_t)row * Dc + d] = o;
        if (outb) outb[(size_t)row * Dc + d] = f2bf(o);
    }
}

// ---------------------------------------------------------------------------
// K6: transpose src[B,N,D] -> out[B,D,N]
// ---------------------------------------------------------------------------
__global__ void transpose_out_kernel(const float* __restrict__ src,
                                     float* __restrict__ out) {
    __shared__ float tile[32][33];
    int b  = blockIdx.z;
    int n0 = blockIdx.x * 32, d0 = blockIdx.y * 32;
    int tx = threadIdx.x, ty = threadIdx.y;
    tile[ty][tx] = src[((size_t)b * Nc + (n0 + ty)) * Dc + (d0 + tx)];
    __syncthreads();
    out[((size_t)b * Dc + (d0 + ty)) * Nc + (n0 + tx)] = tile[tx][ty];
}

// ---------------------------------------------------------------------------
extern "C" void kernel_launch(void* const* d_in, const int* in_sizes, int n_in,
                              void* d_out, int out_size, void* d_ws, size_t ws_size,
                              hipStream_t stream) {
    (void)in_sizes; (void)n_in; (void)out_size; (void)ws_size;
    const float* x      = (const float*)d_in[0];
    const float* qmask  = (const float*)d_in[1];
    const float* so_w   = (const float*)d_in[2];
    const float* so_b   = (const float*)d_in[3];
    const float* aw_w   = (const float*)d_in[4];
    const float* aw_b   = (const float*)d_in[5];
    const float* vp_w   = (const float*)d_in[6];
    const float* vp_b   = (const float*)d_in[7];
    const float* op_w   = (const float*)d_in[8];
    const float* op_b   = (const float*)d_in[9];
    const float* ln1_g  = (const float*)d_in[10];
    const float* ln1_b  = (const float*)d_in[11];
    const float* w1     = (const float*)d_in[12];
    const float* w2     = (const float*)d_in[13];
    const float* ln2_g  = (const float*)d_in[14];
    const float* ln2_b  = (const float*)d_in[15];
    const float* lvl    = (const float*)d_in[16];
    float* out = (float*)d_out;

    // Workspace layout (~129 MB):
    //   src_f   [BN,384] f32  — residual 1, then q1 (in-place LN1), then q2
    //   value_f [BN,384] f32  — vp out, then op out, then FFN2 out
    //   src_bf  [BN,384] bf16 — vp GEMM input
    //   qpos_bf [BN,384] bf16 — so/aw input; then attn_bf (gather out);
    //                            then q1_bf (ln1 out)  [sequentially dead]
    //   hbuf_bf [BN,1152] bf16 — FFN hidden; so_f/aw_f overlay it early (f32)
    //   wbuf    [1304064] bf16 weights; cum_y/cum_x f32
    float*  ws      = (float*)d_ws;
    float*  src_f   = ws;                         // 6291456 f
    float*  value_f = src_f + 6291456;            // 6291456 f
    ushort* src_bf  = (ushort*)(value_f + 6291456);   // 6291456 us
    ushort* qpos_bf = src_bf + 6291456;           // 6291456 us
    ushort* hbuf_bf = qpos_bf + 6291456;          // 18874368 us
    float*  so_f    = (float*)hbuf_bf;            // 3538944 f (overlay)
    float*  aw_f    = so_f + 3538944;             // 1769472 f (overlay)
    ushort* wbuf    = hbuf_bf + 18874368;         // 1304064 us
    float*  cum_y   = (float*)(wbuf + 1304064);   // 16384 f
    float*  cum_x   = cum_y + 16384;              // 16384 f

    const ushort* so_wb = wbuf;
    const ushort* aw_wb = so_wb + SOW_N;
    const ushort* vp_wb = aw_wb + AWW_N;
    const ushort* op_wb = vp_wb + VPW_N;
    const ushort* w1_b  = op_wb + OPW_N;
    const ushort* w2_b  = w1_b + W1_N;

    // 0) mask cumsums + weight conversion
    cumsum_mask_kernel<<<2, 256, 0, stream>>>(qmask, cum_y, cum_x);
    convert_weights_kernel<<<(WTOT + 255) / 256, 256, 0, stream>>>(
        so_w, aw_w, vp_w, op_w, w1, w2, wbuf);
    // 1) transpose + pos encode
    transpose_pos_kernel<<<dim3(Nc / 32, Dc / 32, Bc), dim3(32, 32), 0, stream>>>(
        x, cum_y, cum_x, lvl, src_f, src_bf, qpos_bf);
    // 2) sampling offsets / attention weights / value projection
    gemm_bf16_kernel<<<dim3(2, BNc / 128), 256, 0, stream>>>(
        qpos_bf, so_wb, so_b, so_f, nullptr, 216, Dc, 0, nullptr);
    gemm_bf16_kernel<<<dim3(1, BNc / 128), 256, 0, stream>>>(
        qpos_bf, aw_wb, aw_b, aw_f, nullptr, 108, Dc, 0, nullptr);
    gemm_bf16_kernel<<<dim3(3, BNc / 128), 256, 0, stream>>>(
        src_bf, vp_wb, vp_b, value_f, nullptr, Dc, Dc, 0, qmask);
    // 3) softmax over P
    softmax_p_kernel<<<(BNc * Mc) / 256, 256, 0, stream>>>(aw_f);
    // 4) deformable gather -> attn_bf (overwrites qpos_bf region; qpos dead)
    deform_attn_kernel<<<(BNc * Mc) / 8, 256, 0, stream>>>(
        value_f, so_f, aw_f, qpos_bf);
    // 5) output projection (value_f dead after gather; reuse as op out)
    gemm_bf16_kernel<<<dim3(3, BNc / 128), 256, 0, stream>>>(
        qpos_bf, op_wb, op_b, value_f, nullptr, Dc, Dc, 0, nullptr);
    // 6) q1 = LN(src + attnproj) — in place into src_f, bf16 copy into qpos_bf
    ln_residual_kernel<<<BNc, 128, 0, stream>>>(
        src_f, value_f, ln1_g, ln1_b, src_f, qpos_bf);
    // 7) FFN
    gemm_bf16_kernel<<<dim3(9, BNc / 128), 256, 0, stream>>>(
        qpos_bf, w1_b, nullptr, nullptr, hbuf_bf, DFFc, Dc, 1, nullptr);
    gemm_bf16_kernel<<<dim3(3, BNc / 128), 256, 0, stream>>>(
        hbuf_bf, w2_b, nullptr, value_f, nullptr, Dc, DFFc, 0, nullptr);
    // 8) q2 = LN(q1 + ffn2) — in place into src_f
    ln_residual_kernel<<<BNc, 128, 0, stream>>>(
        src_f, value_f, ln2_g, ln2_b, src_f, nullptr);
    // 9) transpose to [B,D,H,W]
    transpose_out_kernel<<<dim3(Nc / 32, Dc / 32, Bc), dim3(32, 32), 0, stream>>>(
        src_f, out);
}

// Round 3
// 392.746 us; speedup vs baseline: 2.5032x; 1.3517x over previous
//
#include <hip/hip_runtime.h>
#include <math.h>

// Problem constants
#define Bc   4
#define Hc   64
#define Wc   64
#define Dc   384
#define Nc   4096      // H*W
#define Mc   12
#define Pc   9
#define DHc  32
#define DFFc 1152
#define BNc  (Bc*Nc)   // 16384

typedef __attribute__((ext_vector_type(8))) short short8;
typedef __attribute__((ext_vector_type(4))) float floatx4;

__device__ __forceinline__ ushort f2bf(float f) {
    union { float f; unsigned u; } v; v.f = f;
    unsigned r = v.u + 0x7fffu + ((v.u >> 16) & 1u);   // RNE
    return (ushort)(r >> 16);
}

// ---------------------------------------------------------------------------
// K0: cumsum of not_mask along H (cum_y) and W (cum_x)
// ---------------------------------------------------------------------------
__global__ void cumsum_mask_kernel(const float* __restrict__ qmask,
                                   float* __restrict__ cum_y,
                                   float* __restrict__ cum_x) {
    int t = blockIdx.x * blockDim.x + threadIdx.x;
    if (t < Bc * Wc) {
        int b = t / Wc, w = t % Wc;
        float run = 0.f;
        for (int h = 0; h < Hc; ++h) {
            float nm = (qmask[(b * Hc + h) * Wc + w] == 255.0f) ? 0.f : 1.f;
            run += nm;
            cum_y[(b * Hc + h) * Wc + w] = run;
        }
    } else if (t < Bc * Wc + Bc * Hc) {
        int t2 = t - Bc * Wc;
        int b = t2 / Hc, h = t2 % Hc;
        float run = 0.f;
        for (int w = 0; w < Wc; ++w) {
            float nm = (qmask[(b * Hc + h) * Wc + w] == 255.0f) ? 0.f : 1.f;
            run += nm;
            cum_x[(b * Hc + h) * Wc + w] = run;
        }
    }
}

// ---------------------------------------------------------------------------
// K1: transpose x[B,D,N] -> src_f[B,N,D] (fp32) + src_bf (bf16);
//     qpos_bf = bf16(src + sine_pos + level_embed)
// ---------------------------------------------------------------------------
__global__ void transpose_pos_kernel(const float* __restrict__ x,
                                     const float* __restrict__ cum_y,
                                     const float* __restrict__ cum_x,
                                     const float* __restrict__ level_embed,
                                     float* __restrict__ src_f,
                                     ushort* __restrict__ src_bf,
                                     ushort* __restrict__ qpos_bf) {
    __shared__ float tile[32][33];
    int b  = blockIdx.z;
    int n0 = blockIdx.x * 32, d0 = blockIdx.y * 32;
    int tx = threadIdx.x, ty = threadIdx.y;
    tile[ty][tx] = x[((size_t)b * Dc + (d0 + ty)) * Nc + (n0 + tx)];
    __syncthreads();
    int n = n0 + ty, d = d0 + tx;
    float v = tile[tx][ty];
    size_t oi = ((size_t)b * Nc + n) * Dc + d;
    src_f[oi]  = v;
    src_bf[oi] = f2bf(v);
    int h = n >> 6, w = n & 63;
    const float TWO_PI = 6.28318530717958647692f;
    float vy = cum_y[(b * Hc + h) * Wc + w] /
               (cum_y[(b * Hc + (Hc - 1)) * Wc + w] + 1e-6f) * TWO_PI;
    float vx = cum_x[(b * Hc + h) * Wc + w] /
               (cum_x[(b * Hc + h) * Wc + (Wc - 1)] + 1e-6f) * TWO_PI;
    int   i  = (d < 192) ? d : d - 192;
    float vv = (d < 192) ? vy : vx;
    float dt  = powf(10000.0f, (float)(i >> 1) * (2.0f / 192.0f));
    float ang = vv / dt;
    float pe  = (i & 1) ? cosf(ang) : sinf(ang);
    qpos_bf[oi] = f2bf(v + pe + level_embed[d]);
}

// ---------------------------------------------------------------------------
// K1b: convert all weight matrices fp32 -> bf16; concat so/aw biases (fp32)
//      wbuf layout: [so_w|aw_w] (=soaw 324x384), vp_w, op_w, w1, w2
// ---------------------------------------------------------------------------
#define SOW_N  82944     // 216*384
#define AWW_N  41472     // 108*384
#define VPW_N  147456    // 384*384
#define OPW_N  147456
#define W1_N   442368    // 1152*384
#define W2_N   442368    // 384*1152
#define WTOT   1304064

__global__ void convert_weights_kernel(const float* __restrict__ so_w,
                                       const float* __restrict__ aw_w,
                                       const float* __restrict__ vp_w,
                                       const float* __restrict__ op_w,
                                       const float* __restrict__ w1,
                                       const float* __restrict__ w2,
                                       const float* __restrict__ so_b,
                                       const float* __restrict__ aw_b,
                                       ushort* __restrict__ out,
                                       float* __restrict__ bias_out) {
    int i = blockIdx.x * 256 + threadIdx.x;
    if (i >= WTOT) {
        int j = i - WTOT;
        if (j < 324) bias_out[j] = (j < 216) ? so_b[j] : aw_b[j - 216];
        return;
    }
    float v;
    int j = i;
    if (j < SOW_N) v = so_w[j];
    else if ((j -= SOW_N) < AWW_N) v = aw_w[j];
    else if ((j -= AWW_N) < VPW_N) v = vp_w[j];
    else if ((j -= VPW_N) < OPW_N) v = op_w[j];
    else if ((j -= OPW_N) < W1_N)  v = w1[j];
    else { j -= W1_N; v = w2[j]; }
    out[i] = f2bf(v);
}

// ---------------------------------------------------------------------------
// K2: bf16 MFMA GEMM  C[16384,Nout] = A[16384,K](bf16) * Wt[Nout,K](bf16)^T
// ---------------------------------------------------------------------------
__global__ __launch_bounds__(256) void gemm_bf16_kernel(
        const ushort* __restrict__ A, const ushort* __restrict__ Wt,
        const float* __restrict__ bias,
        float* __restrict__ Cf, ushort* __restrict__ Cb,
        int Nout, int K, int relu, const float* __restrict__ qmask) {
    __shared__ ushort As[128 * 40];
    __shared__ ushort Bs[128 * 40];
    const int tid  = threadIdx.x;
    const int m0   = blockIdx.y * 128;
    const int n0   = blockIdx.x * 128;
    const int lane = tid & 63;
    const int wv   = tid >> 6;
    const int wr   = (wv >> 1) * 64;
    const int wc   = (wv & 1) * 64;
    const int quad = lane >> 4;
    const int lrow = lane & 15;

    floatx4 acc[4][4];
    #pragma unroll
    for (int i = 0; i < 4; ++i)
        #pragma unroll
        for (int j = 0; j < 4; ++j)
            acc[i][j] = (floatx4)(0.f);

    for (int k0 = 0; k0 < K; k0 += 32) {
        #pragma unroll
        for (int s = 0; s < 2; ++s) {
            int seg = tid + s * 256;
            int row = seg >> 2;
            int c   = (seg & 3) * 8;
            short8 av = *(const short8*)(A + (size_t)(m0 + row) * K + k0 + c);
            *(short8*)(&As[row * 40 + c]) = av;
            int nr = n0 + row;
            short8 bv = (short8)(0);
            if (nr < Nout) bv = *(const short8*)(Wt + (size_t)nr * K + k0 + c);
            *(short8*)(&Bs[row * 40 + c]) = bv;
        }
        __syncthreads();
        short8 afr[4], bfr[4];
        #pragma unroll
        for (int i = 0; i < 4; ++i)
            afr[i] = *(const short8*)(&As[(wr + i * 16 + lrow) * 40 + quad * 8]);
        #pragma unroll
        for (int j = 0; j < 4; ++j)
            bfr[j] = *(const short8*)(&Bs[(wc + j * 16 + lrow) * 40 + quad * 8]);
        #pragma unroll
        for (int i = 0; i < 4; ++i)
            #pragma unroll
            for (int j = 0; j < 4; ++j)
                acc[i][j] = __builtin_amdgcn_mfma_f32_16x16x32_bf16(
                    afr[i], bfr[j], acc[i][j], 0, 0, 0);
        __syncthreads();
    }

    #pragma unroll
    for (int i = 0; i < 4; ++i) {
        #pragma unroll
        for (int j = 0; j < 4; ++j) {
            int col = n0 + wc + j * 16 + lrow;
            if (col >= Nout) continue;
            float bsv = bias ? bias[col] : 0.f;
            #pragma unroll
            for (int r = 0; r < 4; ++r) {
                int row = m0 + wr + i * 16 + quad * 4 + r;
                float v = acc[i][j][r] + bsv;
                if (relu) v = fmaxf(v, 0.f);
                if (qmask && qmask[row] == 255.0f) v = 0.f;
                if (Cf) Cf[(size_t)row * Nout + col] = v;
                if (Cb) Cb[(size_t)row * Nout + col] = f2bf(v);
            }
        }
    }
}

// ---------------------------------------------------------------------------
// K3: softmax over P=9 per (b,n,m) from soaw[:,216+m*9 ..], pack to 12 floats
// ---------------------------------------------------------------------------
__global__ void softmax_pack_kernel(const float* __restrict__ soaw,
                                    float* __restrict__ pack) {
    int idx = blockIdx.x * 256 + threadIdx.x;     // bn*M + m
    if (idx >= BNc * Mc) return;
    int m  = idx % Mc;
    int bn = idx / Mc;
    const float* l = soaw + (size_t)bn * 324 + 216 + m * Pc;
    float e[Pc];
    float mx = l[0];
    #pragma unroll
    for (int i = 1; i < Pc; ++i) mx = fmaxf(mx, l[i]);
    float s = 0.f;
    #pragma unroll
    for (int i = 0; i < Pc; ++i) { e[i] = expf(l[i] - mx); s += e[i]; }
    float inv = 1.f / s;
    float* o = pack + (size_t)idx * 12;
    #pragma unroll
    for (int i = 0; i < Pc; ++i) o[i] = e[i] * inv;
    o[9] = 0.f; o[10] = 0.f; o[11] = 0.f;
}

// ---------------------------------------------------------------------------
// K4: deformable attention gather v2.
//     8-lane group per (b,n,m); lane = 4 channels (bf16x4 = 8B loads).
// ---------------------------------------------------------------------------
__global__ __launch_bounds__(256) void deform_attn_kernel(
        const ushort* __restrict__ value_bf, const float* __restrict__ soaw,
        const float* __restrict__ pack, ushort* __restrict__ out) {
    int gid = blockIdx.x * 32 + (threadIdx.x >> 3);   // (b*N+n)*M + m
    int l8  = threadIdx.x & 7;                        // channel quad
    int m  = gid % Mc;
    int bn = gid / Mc;
    int b  = bn >> 12;
    int n  = bn & 4095;
    int h  = n >> 6, w = n & 63;
    const float* sop = soaw + (size_t)bn * 324 + m * 18;
    const float* awp = pack + (size_t)gid * 12;
    float4 aw0 = *(const float4*)(awp);
    float4 aw1 = *(const float4*)(awp + 4);
    float  aw8 = awp[8];
    float awv[Pc] = {aw0.x, aw0.y, aw0.z, aw0.w, aw1.x, aw1.y, aw1.z, aw1.w, aw8};
    const ushort* vb = value_bf + ((size_t)b * Nc) * Dc + m * DHc + l8 * 4;
    float a0 = 0.f, a1 = 0.f, a2 = 0.f, a3 = 0.f;
    #pragma unroll
    for (int p = 0; p < Pc; ++p) {
        float2 so2 = *(const float2*)(sop + p * 2);
        float px = (float)w + so2.x;     // (ref + so/64)*64 - 0.5 simplifies
        float py = (float)h + so2.y;
        float x0f = floorf(px), y0f = floorf(py);
        float lx = px - x0f, ly = py - y0f;
        int x0 = (int)x0f, y0 = (int)y0f;
        int x1 = x0 + 1,  y1 = y0 + 1;
        float a = awv[p];
        float w00 = (1.f - lx) * (1.f - ly) * a;
        float w01 = lx * (1.f - ly) * a;
        float w10 = (1.f - lx) * ly * a;
        float w11 = lx * ly * a;
        bool bx0 = (unsigned)x0 < 64u, bx1 = (unsigned)x1 < 64u;
        bool by0 = (unsigned)y0 < 64u, by1 = (unsigned)y1 < 64u;
        w00 = (bx0 && by0) ? w00 : 0.f;
        w01 = (bx1 && by0) ? w01 : 0.f;
        w10 = (bx0 && by1) ? w10 : 0.f;
        w11 = (bx1 && by1) ? w11 : 0.f;
        int cx0 = min(max(x0, 0), 63), cx1 = min(max(x1, 0), 63);
        int cy0 = min(max(y0, 0), 63), cy1 = min(max(y1, 0), 63);
        uint2 q00 = *(const uint2*)(vb + (size_t)(cy0 * 64 + cx0) * Dc);
        uint2 q01 = *(const uint2*)(vb + (size_t)(cy0 * 64 + cx1) * Dc);
        uint2 q10 = *(const uint2*)(vb + (size_t)(cy1 * 64 + cx0) * Dc);
        uint2 q11 = *(const uint2*)(vb + (size_t)(cy1 * 64 + cx1) * Dc);
        union { unsigned u; float f; } t;
        #define ACC4(q, wg) \
            t.u = (q).x << 16;         a0 += (wg) * t.f; \
            t.u = (q).x & 0xffff0000u; a1 += (wg) * t.f; \
            t.u = (q).y << 16;         a2 += (wg) * t.f; \
            t.u = (q).y & 0xffff0000u; a3 += (wg) * t.f;
        ACC4(q00, w00) ACC4(q01, w01) ACC4(q10, w10) ACC4(q11, w11)
        #undef ACC4
    }
    ushort4 o;
    o.x = f2bf(a0); o.y = f2bf(a1); o.z = f2bf(a2); o.w = f2bf(a3);
    *(ushort4*)(out + (size_t)bn * Dc + m * DHc + l8 * 4) = o;
}

// ---------------------------------------------------------------------------
// K5: out = LayerNorm(a + r) * g + beta ; optional bf16 copy. In-place safe.
// ---------------------------------------------------------------------------
__global__ __launch_bounds__(128) void ln_residual_kernel(
        const float* a, const float* r,
        const float* g, const float* beta,
        float* out, ushort* outb) {
    int row = blockIdx.x;
    int tid = threadIdx.x;
    float v[3];
    float s1 = 0.f, s2 = 0.f;
    #pragma unroll
    for (int i = 0; i < 3; ++i) {
        int d = i * 128 + tid;
        float t = a[(size_t)row * Dc + d] + r[(size_t)row * Dc + d];
        v[i] = t; s1 += t; s2 += t * t;
    }
    __shared__ float sh1[128], sh2[128];
    sh1[tid] = s1; sh2[tid] = s2;
    __syncthreads();
    for (int off = 64; off > 0; off >>= 1) {
        if (tid < off) { sh1[tid] += sh1[tid + off]; sh2[tid] += sh2[tid + off]; }
        __syncthreads();
    }
    float mu  = sh1[0] * (1.0f / Dc);
    float var = sh2[0] * (1.0f / Dc) - mu * mu;
    float rs  = rsqrtf(var + 1e-5f);
    #pragma unroll
    for (int i = 0; i < 3; ++i) {
        int d = i * 128 + tid;
        float o = (v[i] - mu) * rs * g[d] + beta[d];
        out[(size_t)row * Dc + d] = o;
        if (outb) outb[(size_t)row * Dc + d] = f2bf(o);
    }
}

// ---------------------------------------------------------------------------
// K6: transpose src[B,N,D] -> out[B,D,N]
// ---------------------------------------------------------------------------
__global__ void transpose_out_kernel(const float* __restrict__ src,
                                     float* __restrict__ out) {
    __shared__ float tile[32][33];
    int b  = blockIdx.z;
    int n0 = blockIdx.x * 32, d0 = blockIdx.y * 32;
    int tx = threadIdx.x, ty = threadIdx.y;
    tile[ty][tx] = src[((size_t)b * Nc + (n0 + ty)) * Dc + (d0 + tx)];
    __syncthreads();
    out[((size_t)b * Dc + (d0 + ty)) * Nc + (n0 + tx)] = tile[tx][ty];
}

// ---------------------------------------------------------------------------
extern "C" void kernel_launch(void* const* d_in, const int* in_sizes, int n_in,
                              void* d_out, int out_size, void* d_ws, size_t ws_size,
                              hipStream_t stream) {
    (void)in_sizes; (void)n_in; (void)out_size; (void)ws_size;
    const float* x      = (const float*)d_in[0];
    const float* qmask  = (const float*)d_in[1];
    const float* so_w   = (const float*)d_in[2];
    const float* so_b   = (const float*)d_in[3];
    const float* aw_w   = (const float*)d_in[4];
    const float* aw_b   = (const float*)d_in[5];
    const float* vp_w   = (const float*)d_in[6];
    const float* vp_b   = (const float*)d_in[7];
    const float* op_w   = (const float*)d_in[8];
    const float* op_b   = (const float*)d_in[9];
    const float* ln1_g  = (const float*)d_in[10];
    const float* ln1_b  = (const float*)d_in[11];
    const float* w1     = (const float*)d_in[12];
    const float* w2     = (const float*)d_in[13];
    const float* ln2_g  = (const float*)d_in[14];
    const float* ln2_b  = (const float*)d_in[15];
    const float* lvl    = (const float*)d_in[16];
    float* out = (float*)d_out;

    // Workspace layout (~129 MB in floats):
    float*  ws       = (float*)d_ws;
    float*  src_f    = ws;                          // 6291456 f (residual/q1/q2)
    float*  proj_f   = src_f + 6291456;             // 6291456 f (op out, FFN2 out)
    ushort* src_bf   = (ushort*)(proj_f + 6291456); // 6291456 us
    ushort* qpos_bf  = src_bf + 6291456;            // 6291456 us (qpos->attn->q1_bf)
    ushort* value_bf = qpos_bf + 6291456;           // 6291456 us
    ushort* hbuf_bf  = value_bf + 6291456;          // 18874368 us (FFN hidden)
    float*  soaw_f   = (float*)hbuf_bf;             // 5308416 f overlay (dead pre-FFN1)
    float*  pack_f   = soaw_f + 5308416;            // 2359296 f overlay (dead pre-FFN1)
    ushort* wbuf     = hbuf_bf + 18874368;          // 1304064 us
    float*  soaw_bias= (float*)(wbuf + 1304064);    // 324 f
    float*  cum_y    = soaw_bias + 324;             // 16384 f
    float*  cum_x    = cum_y + 16384;               // 16384 f

    const ushort* soaw_wb = wbuf;                   // [324,384] (so_w ++ aw_w)
    const ushort* vp_wb = soaw_wb + SOW_N + AWW_N;
    const ushort* op_wb = vp_wb + VPW_N;
    const ushort* w1_b  = op_wb + OPW_N;
    const ushort* w2_b  = w1_b + W1_N;

    // 0) mask cumsums + weight conversion (+bias concat)
    cumsum_mask_kernel<<<2, 256, 0, stream>>>(qmask, cum_y, cum_x);
    convert_weights_kernel<<<(WTOT + 324 + 255) / 256, 256, 0, stream>>>(
        so_w, aw_w, vp_w, op_w, w1, w2, so_b, aw_b, wbuf, soaw_bias);
    // 1) transpose + pos encode
    transpose_pos_kernel<<<dim3(Nc / 32, Dc / 32, Bc), dim3(32, 32), 0, stream>>>(
        x, cum_y, cum_x, lvl, src_f, src_bf, qpos_bf);
    // 2) merged sampling-offset + attn-weight projection; value projection
    gemm_bf16_kernel<<<dim3(3, BNc / 128), 256, 0, stream>>>(
        qpos_bf, soaw_wb, soaw_bias, soaw_f, nullptr, 324, Dc, 0, nullptr);
    gemm_bf16_kernel<<<dim3(3, BNc / 128), 256, 0, stream>>>(
        src_bf, vp_wb, vp_b, nullptr, value_bf, Dc, Dc, 0, qmask);
    // 3) softmax + pack attention weights
    softmax_pack_kernel<<<(BNc * Mc + 255) / 256, 256, 0, stream>>>(soaw_f, pack_f);
    // 4) deformable gather -> attn_bf (into qpos_bf region; qpos dead)
    deform_attn_kernel<<<(BNc * Mc) / 32, 256, 0, stream>>>(
        value_bf, soaw_f, pack_f, qpos_bf);
    // 5) output projection
    gemm_bf16_kernel<<<dim3(3, BNc / 128), 256, 0, stream>>>(
        qpos_bf, op_wb, op_b, proj_f, nullptr, Dc, Dc, 0, nullptr);
    // 6) q1 = LN(src + attnproj) — in place, bf16 copy to qpos_bf
    ln_residual_kernel<<<BNc, 128, 0, stream>>>(
        src_f, proj_f, ln1_g, ln1_b, src_f, qpos_bf);
    // 7) FFN
    gemm_bf16_kernel<<<dim3(9, BNc / 128), 256, 0, stream>>>(
        qpos_bf, w1_b, nullptr, nullptr, hbuf_bf, DFFc, Dc, 1, nullptr);
    gemm_bf16_kernel<<<dim3(3, BNc / 128), 256, 0, stream>>>(
        hbuf_bf, w2_b, nullptr, proj_f, nullptr, Dc, DFFc, 0, nullptr);
    // 8) q2 = LN(q1 + ffn2) — in place
    ln_residual_kernel<<<BNc, 128, 0, stream>>>(
        src_f, proj_f, ln2_g, ln2_b, src_f, nullptr);
    // 9) transpose to [B,D,H,W]
    transpose_out_kernel<<<dim3(Nc / 32, Dc / 32, Bc), dim3(32, 32), 0, stream>>>(
        src_f, out);
}

// Round 4
// 340.455 us; speedup vs baseline: 2.8876x; 1.1536x over previous
//
#include <hip/hip_runtime.h>
#include <math.h>

// Problem constants
#define Bc   4
#define Hc   64
#define Wc   64
#define Dc   384
#define Nc   4096      // H*W
#define Mc   12
#define Pc   9
#define DHc  32
#define DFFc 1152
#define BNc  (Bc*Nc)   // 16384

typedef __attribute__((ext_vector_type(8))) short short8;
typedef __attribute__((ext_vector_type(4))) float floatx4;

__device__ __forceinline__ ushort f2bf(float f) {
    union { float f; unsigned u; } v; v.f = f;
    unsigned r = v.u + 0x7fffu + ((v.u >> 16) & 1u);   // RNE
    return (ushort)(r >> 16);
}

// async global->LDS, 16B per lane; LDS dest = wave-uniform base + lane*16
__device__ __forceinline__ void gload_lds16(const void* g, void* l) {
    __builtin_amdgcn_global_load_lds(
        (const __attribute__((address_space(1))) void*)(uintptr_t)g,
        (__attribute__((address_space(3))) void*)(uintptr_t)l,
        16, 0, 0);
}

// ---------------------------------------------------------------------------
// K0: cumsum of not_mask along H (cum_y) and W (cum_x)
// ---------------------------------------------------------------------------
__global__ void cumsum_mask_kernel(const float* __restrict__ qmask,
                                   float* __restrict__ cum_y,
                                   float* __restrict__ cum_x) {
    int t = blockIdx.x * blockDim.x + threadIdx.x;
    if (t < Bc * Wc) {
        int b = t / Wc, w = t % Wc;
        float run = 0.f;
        for (int h = 0; h < Hc; ++h) {
            float nm = (qmask[(b * Hc + h) * Wc + w] == 255.0f) ? 0.f : 1.f;
            run += nm;
            cum_y[(b * Hc + h) * Wc + w] = run;
        }
    } else if (t < Bc * Wc + Bc * Hc) {
        int t2 = t - Bc * Wc;
        int b = t2 / Hc, h = t2 % Hc;
        float run = 0.f;
        for (int w = 0; w < Wc; ++w) {
            float nm = (qmask[(b * Hc + h) * Wc + w] == 255.0f) ? 0.f : 1.f;
            run += nm;
            cum_x[(b * Hc + h) * Wc + w] = run;
        }
    }
}

// ---------------------------------------------------------------------------
// K1: transpose x[B,D,N] -> src_f[B,N,D] (fp32) + src_bf (bf16);
//     qpos_bf = bf16(src + sine_pos + level_embed). Fast-math trig.
// ---------------------------------------------------------------------------
__global__ void transpose_pos_kernel(const float* __restrict__ x,
                                     const float* __restrict__ cum_y,
                                     const float* __restrict__ cum_x,
                                     const float* __restrict__ level_embed,
                                     float* __restrict__ src_f,
                                     ushort* __restrict__ src_bf,
                                     ushort* __restrict__ qpos_bf) {
    __shared__ float tile[32][33];
    int b  = blockIdx.z;
    int n0 = blockIdx.x * 32, d0 = blockIdx.y * 32;
    int tx = threadIdx.x, ty = threadIdx.y;
    tile[ty][tx] = x[((size_t)b * Dc + (d0 + ty)) * Nc + (n0 + tx)];
    __syncthreads();
    int n = n0 + ty, d = d0 + tx;
    float v = tile[tx][ty];
    size_t oi = ((size_t)b * Nc + n) * Dc + d;
    src_f[oi]  = v;
    src_bf[oi] = f2bf(v);
    int h = n >> 6, w = n & 63;
    const float TWO_PI = 6.28318530717958647692f;
    float vy = cum_y[(b * Hc + h) * Wc + w] /
               (cum_y[(b * Hc + (Hc - 1)) * Wc + w] + 1e-6f) * TWO_PI;
    float vx = cum_x[(b * Hc + h) * Wc + w] /
               (cum_x[(b * Hc + h) * Wc + (Wc - 1)] + 1e-6f) * TWO_PI;
    int   i  = (d < 192) ? d : d - 192;
    float vv = (d < 192) ? vy : vx;
    // 10000^(-e) = exp2(-e*log2(10000)), log2(10000)=13.287712379549449
    float e   = (float)(i >> 1) * (2.0f / 192.0f);
    float idt = exp2f(e * -13.28771237954945f);
    float ang = vv * idt;
    float pe  = (i & 1) ? __cosf(ang) : __sinf(ang);
    qpos_bf[oi] = f2bf(v + pe + level_embed[d]);
}

// ---------------------------------------------------------------------------
// K1b: convert all weight matrices fp32 -> bf16; concat so/aw biases (fp32)
// ---------------------------------------------------------------------------
#define SOW_N  82944     // 216*384
#define AWW_N  41472     // 108*384
#define VPW_N  147456    // 384*384
#define OPW_N  147456
#define W1_N   442368    // 1152*384
#define W2_N   442368    // 384*1152
#define WTOT   1304064

__global__ void convert_weights_kernel(const float* __restrict__ so_w,
                                       const float* __restrict__ aw_w,
                                       const float* __restrict__ vp_w,
                                       const float* __restrict__ op_w,
                                       const float* __restrict__ w1,
                                       const float* __restrict__ w2,
                                       const float* __restrict__ so_b,
                                       const float* __restrict__ aw_b,
                                       ushort* __restrict__ out,
                                       float* __restrict__ bias_out) {
    int i = blockIdx.x * 256 + threadIdx.x;
    if (i >= WTOT) {
        int j = i - WTOT;
        if (j < 324) bias_out[j] = (j < 216) ? so_b[j] : aw_b[j - 216];
        return;
    }
    float v;
    int j = i;
    if (j < SOW_N) v = so_w[j];
    else if ((j -= SOW_N) < AWW_N) v = aw_w[j];
    else if ((j -= AWW_N) < VPW_N) v = vp_w[j];
    else if ((j -= VPW_N) < OPW_N) v = op_w[j];
    else if ((j -= OPW_N) < W1_N)  v = w1[j];
    else { j -= W1_N; v = w2[j]; }
    out[i] = f2bf(v);
}

// ---------------------------------------------------------------------------
// K2: bf16 MFMA GEMM, m97-style: global_load_lds(16B) staging into unpadded
//     [128][32] LDS tiles, ds_read_b128 fragments, 16x mfma_16x16x32/K-step.
//     C[16384,Nout] = A[16384,K] * Wt[Nout,K]^T (+bias)(+relu)(+rowmask)
//     Weight tile over-reads past Nout must stay inside the weight buffer
//     (guaranteed by wbuf layout); epilogue guards col < Nout.
// ---------------------------------------------------------------------------
__global__ __launch_bounds__(256) void gemm_bf16_kernel(
        const ushort* __restrict__ A, const ushort* __restrict__ Wt,
        const float* __restrict__ bias,
        float* __restrict__ Cf, ushort* __restrict__ Cb,
        int Nout, int K, int relu, const float* __restrict__ qmask) {
    __shared__ ushort As[128 * 32];
    __shared__ ushort Bs[128 * 32];
    const int tid  = threadIdx.x;
    const int m0   = blockIdx.y * 128;
    const int n0   = blockIdx.x * 128;
    const int lane = tid & 63;
    const int wv   = tid >> 6;
    const int wr   = (wv >> 1) * 64;
    const int wc   = (wv & 1) * 64;
    const int quad = lane >> 4;
    const int lrow = lane & 15;
    // staging: wave wv covers tile rows [wv*32, wv*32+32); inst s: +s*16
    const int srow = wv * 32 + (lane >> 2);
    const int scol = (lane & 3) * 8;

    floatx4 acc[4][4];
    #pragma unroll
    for (int i = 0; i < 4; ++i)
        #pragma unroll
        for (int j = 0; j < 4; ++j)
            acc[i][j] = (floatx4)(0.f);

    for (int k0 = 0; k0 < K; k0 += 32) {
        #pragma unroll
        for (int s = 0; s < 2; ++s) {
            gload_lds16(A  + (size_t)(m0 + srow + s * 16) * K + k0 + scol,
                        As + wv * 1024 + s * 512);
            gload_lds16(Wt + (size_t)(n0 + srow + s * 16) * K + k0 + scol,
                        Bs + wv * 1024 + s * 512);
        }
        __syncthreads();
        short8 afr[4], bfr[4];
        #pragma unroll
        for (int i = 0; i < 4; ++i)
            afr[i] = *(const short8*)(&As[(wr + i * 16 + lrow) * 32 + quad * 8]);
        #pragma unroll
        for (int j = 0; j < 4; ++j)
            bfr[j] = *(const short8*)(&Bs[(wc + j * 16 + lrow) * 32 + quad * 8]);
        #pragma unroll
        for (int i = 0; i < 4; ++i)
            #pragma unroll
            for (int j = 0; j < 4; ++j)
                acc[i][j] = __builtin_amdgcn_mfma_f32_16x16x32_bf16(
                    afr[i], bfr[j], acc[i][j], 0, 0, 0);
        __syncthreads();
    }

    // row-mask multipliers (value projection only)
    float mz[4][4];
    #pragma unroll
    for (int i = 0; i < 4; ++i)
        #pragma unroll
        for (int r = 0; r < 4; ++r) {
            int row = m0 + wr + i * 16 + quad * 4 + r;
            mz[i][r] = (qmask && qmask[row] == 255.0f) ? 0.f : 1.f;
        }

    // C/D layout (16x16x32): col = lane&15, row = quad*4 + reg
    #pragma unroll
    for (int i = 0; i < 4; ++i) {
        #pragma unroll
        for (int j = 0; j < 4; ++j) {
            int col = n0 + wc + j * 16 + lrow;
            if (col >= Nout) continue;
            float bsv = bias ? bias[col] : 0.f;
            #pragma unroll
            for (int r = 0; r < 4; ++r) {
                int row = m0 + wr + i * 16 + quad * 4 + r;
                float v = acc[i][j][r] + bsv;
                if (relu) v = fmaxf(v, 0.f);
                v *= mz[i][r];
                if (Cf) Cf[(size_t)row * Nout + col] = v;
                if (Cb) Cb[(size_t)row * Nout + col] = f2bf(v);
            }
        }
    }
}

// ---------------------------------------------------------------------------
// K3: softmax over P=9 per (b,n,m) from soaw[:,216+m*9..], pack to 12 floats
// ---------------------------------------------------------------------------
__global__ void softmax_pack_kernel(const float* __restrict__ soaw,
                                    float* __restrict__ pack) {
    int idx = blockIdx.x * 256 + threadIdx.x;     // bn*M + m
    if (idx >= BNc * Mc) return;
    int m  = idx % Mc;
    int bn = idx / Mc;
    const float* l = soaw + (size_t)bn * 324 + 216 + m * Pc;
    float e[Pc];
    float mx = l[0];
    #pragma unroll
    for (int i = 1; i < Pc; ++i) mx = fmaxf(mx, l[i]);
    float s = 0.f;
    #pragma unroll
    for (int i = 0; i < Pc; ++i) { e[i] = __expf(l[i] - mx); s += e[i]; }
    float inv = 1.f / s;
    float* o = pack + (size_t)idx * 12;
    #pragma unroll
    for (int i = 0; i < Pc; ++i) o[i] = e[i] * inv;
    o[9] = 0.f; o[10] = 0.f; o[11] = 0.f;
}

// ---------------------------------------------------------------------------
// K4: deformable attention gather v3.
//     4-lane group per (b,n,m); lane = 8 channels (bf16x8 = 16B loads).
// ---------------------------------------------------------------------------
__global__ __launch_bounds__(256) void deform_attn_kernel(
        const ushort* __restrict__ value_bf, const float* __restrict__ soaw,
        const float* __restrict__ pack, ushort* __restrict__ out) {
    int gid = blockIdx.x * 64 + (threadIdx.x >> 2);   // (b*N+n)*M + m
    int l4  = threadIdx.x & 3;                        // channel octet
    int m  = gid % Mc;
    int bn = gid / Mc;
    int b  = bn >> 12;
    int n  = bn & 4095;
    int h  = n >> 6, w = n & 63;
    const float* sop = soaw + (size_t)bn * 324 + m * 18;
    const float* awp = pack + (size_t)gid * 12;
    float4 aw0 = *(const float4*)(awp);
    float4 aw1 = *(const float4*)(awp + 4);
    float  aw8 = awp[8];
    float awv[Pc] = {aw0.x, aw0.y, aw0.z, aw0.w, aw1.x, aw1.y, aw1.z, aw1.w, aw8};
    const ushort* vb = value_bf + ((size_t)b * Nc) * Dc + m * DHc + l4 * 8;
    float acc[8] = {0.f, 0.f, 0.f, 0.f, 0.f, 0.f, 0.f, 0.f};
    #pragma unroll
    for (int p = 0; p < Pc; ++p) {
        float2 so2 = *(const float2*)(sop + p * 2);
        float px = (float)w + so2.x;     // (ref + so/64)*64 - 0.5 simplifies
        float py = (float)h + so2.y;
        float x0f = floorf(px), y0f = floorf(py);
        float lx = px - x0f, ly = py - y0f;
        int x0 = (int)x0f, y0 = (int)y0f;
        int x1 = x0 + 1,  y1 = y0 + 1;
        float a = awv[p];
        float w00 = (1.f - lx) * (1.f - ly) * a;
        float w01 = lx * (1.f - ly) * a;
        float w10 = (1.f - lx) * ly * a;
        float w11 = lx * ly * a;
        bool bx0 = (unsigned)x0 < 64u, bx1 = (unsigned)x1 < 64u;
        bool by0 = (unsigned)y0 < 64u, by1 = (unsigned)y1 < 64u;
        w00 = (bx0 && by0) ? w00 : 0.f;
        w01 = (bx1 && by0) ? w01 : 0.f;
        w10 = (bx0 && by1) ? w10 : 0.f;
        w11 = (bx1 && by1) ? w11 : 0.f;
        int cx0 = min(max(x0, 0), 63), cx1 = min(max(x1, 0), 63);
        int cy0 = min(max(y0, 0), 63), cy1 = min(max(y1, 0), 63);
        uint4 q00 = *(const uint4*)(vb + (size_t)(cy0 * 64 + cx0) * Dc);
        uint4 q01 = *(const uint4*)(vb + (size_t)(cy0 * 64 + cx1) * Dc);
        uint4 q10 = *(const uint4*)(vb + (size_t)(cy1 * 64 + cx0) * Dc);
        uint4 q11 = *(const uint4*)(vb + (size_t)(cy1 * 64 + cx1) * Dc);
        union { unsigned u; float f; } t;
        #define ACC2(word, wg, k)                                   \
            t.u = (word) << 16;         acc[k]     += (wg) * t.f;   \
            t.u = (word) & 0xffff0000u; acc[k + 1] += (wg) * t.f;
        #define ACC8(q, wg) \
            ACC2((q).x, wg, 0) ACC2((q).y, wg, 2) ACC2((q).z, wg, 4) ACC2((q).w, wg, 6)
        ACC8(q00, w00) ACC8(q01, w01) ACC8(q10, w10) ACC8(q11, w11)
        #undef ACC8
        #undef ACC2
    }
    short8 o;
    #pragma unroll
    for (int k = 0; k < 8; ++k) o[k] = (short)f2bf(acc[k]);
    *(short8*)(out + (size_t)bn * Dc + m * DHc + l4 * 8) = o;
}

// ---------------------------------------------------------------------------
// K5: out = LayerNorm(a + r) * g + beta ; optional bf16 copy. In-place safe.
//     float4-vectorized: 96 of 128 threads carry data.
// ---------------------------------------------------------------------------
__global__ __launch_bounds__(128) void ln_residual_kernel(
        const float* a, const float* r,
        const float* g, const float* beta,
        float* out, ushort* outb) {
    int row = blockIdx.x;
    int tid = threadIdx.x;
    float4 v = make_float4(0.f, 0.f, 0.f, 0.f);
    if (tid < 96) {
        float4 av = ((const float4*)(a + (size_t)row * Dc))[tid];
        float4 rv = ((const float4*)(r + (size_t)row * Dc))[tid];
        v.x = av.x + rv.x; v.y = av.y + rv.y;
        v.z = av.z + rv.z; v.w = av.w + rv.w;
    }
    float s1 = v.x + v.y + v.z + v.w;
    float s2 = v.x * v.x + v.y * v.y + v.z * v.z + v.w * v.w;
    __shared__ float sh1[128], sh2[128];
    sh1[tid] = s1; sh2[tid] = s2;
    __syncthreads();
    for (int off = 64; off > 0; off >>= 1) {
        if (tid < off) { sh1[tid] += sh1[tid + off]; sh2[tid] += sh2[tid + off]; }
        __syncthreads();
    }
    float mu  = sh1[0] * (1.0f / Dc);
    float var = sh2[0] * (1.0f / Dc) - mu * mu;
    float rs  = rsqrtf(var + 1e-5f);
    if (tid < 96) {
        float4 gv = ((const float4*)g)[tid];
        float4 bv = ((const float4*)beta)[tid];
        float4 o;
        o.x = (v.x - mu) * rs * gv.x + bv.x;
        o.y = (v.y - mu) * rs * gv.y + bv.y;
        o.z = (v.z - mu) * rs * gv.z + bv.z;
        o.w = (v.w - mu) * rs * gv.w + bv.w;
        ((float4*)(out + (size_t)row * Dc))[tid] = o;
        if (outb) {
            ushort4 ob;
            ob.x = f2bf(o.x); ob.y = f2bf(o.y);
            ob.z = f2bf(o.z); ob.w = f2bf(o.w);
            ((ushort4*)(outb + (size_t)row * Dc))[tid] = ob;
        }
    }
}

// ---------------------------------------------------------------------------
// K6: transpose src[B,N,D] -> out[B,D,N]
// ---------------------------------------------------------------------------
__global__ void transpose_out_kernel(const float* __restrict__ src,
                                     float* __restrict__ out) {
    __shared__ float tile[32][33];
    int b  = blockIdx.z;
    int n0 = blockIdx.x * 32, d0 = blockIdx.y * 32;
    int tx = threadIdx.x, ty = threadIdx.y;
    tile[ty][tx] = src[((size_t)b * Nc + (n0 + ty)) * Dc + (d0 + tx)];
    __syncthreads();
    out[((size_t)b * Dc + (d0 + ty)) * Nc + (n0 + tx)] = tile[tx][ty];
}

// ---------------------------------------------------------------------------
extern "C" void kernel_launch(void* const* d_in, const int* in_sizes, int n_in,
                              void* d_out, int out_size, void* d_ws, size_t ws_size,
                              hipStream_t stream) {
    (void)in_sizes; (void)n_in; (void)out_size; (void)ws_size;
    const float* x      = (const float*)d_in[0];
    const float* qmask  = (const float*)d_in[1];
    const float* so_w   = (const float*)d_in[2];
    const float* so_b   = (const float*)d_in[3];
    const float* aw_w   = (const float*)d_in[4];
    const float* aw_b   = (const float*)d_in[5];
    const float* vp_w   = (const float*)d_in[6];
    const float* vp_b   = (const float*)d_in[7];
    const float* op_w   = (const float*)d_in[8];
    const float* op_b   = (const float*)d_in[9];
    const float* ln1_g  = (const float*)d_in[10];
    const float* ln1_b  = (const float*)d_in[11];
    const float* w1     = (const float*)d_in[12];
    const float* w2     = (const float*)d_in[13];
    const float* ln2_g  = (const float*)d_in[14];
    const float* ln2_b  = (const float*)d_in[15];
    const float* lvl    = (const float*)d_in[16];
    float* out = (float*)d_out;

    // Workspace layout (~129 MB in floats):
    float*  ws       = (float*)d_ws;
    float*  src_f    = ws;                          // 6291456 f (residual/q1/q2)
    float*  proj_f   = src_f + 6291456;             // 6291456 f (op out, FFN2 out)
    ushort* src_bf   = (ushort*)(proj_f + 6291456); // 6291456 us
    ushort* qpos_bf  = src_bf + 6291456;            // 6291456 us (qpos->attn->q1_bf)
    ushort* value_bf = qpos_bf + 6291456;           // 6291456 us
    ushort* hbuf_bf  = value_bf + 6291456;          // 18874368 us (FFN hidden)
    float*  soaw_f   = (float*)hbuf_bf;             // 5308416 f overlay (dead pre-FFN1)
    float*  pack_f   = soaw_f + 5308416;            // 2359296 f overlay (dead pre-FFN1)
    ushort* wbuf     = hbuf_bf + 18874368;          // 1304064 us
    float*  soaw_bias= (float*)(wbuf + 1304064);    // 324 f
    float*  cum_y    = soaw_bias + 324;             // 16384 f
    float*  cum_x    = cum_y + 16384;               // 16384 f

    const ushort* soaw_wb = wbuf;                   // [324,384] (so_w ++ aw_w)
    const ushort* vp_wb = soaw_wb + SOW_N + AWW_N;
    const ushort* op_wb = vp_wb + VPW_N;
    const ushort* w1_b  = op_wb + OPW_N;
    const ushort* w2_b  = w1_b + W1_N;

    // 0) mask cumsums + weight conversion (+bias concat)
    cumsum_mask_kernel<<<2, 256, 0, stream>>>(qmask, cum_y, cum_x);
    convert_weights_kernel<<<(WTOT + 324 + 255) / 256, 256, 0, stream>>>(
        so_w, aw_w, vp_w, op_w, w1, w2, so_b, aw_b, wbuf, soaw_bias);
    // 1) transpose + pos encode
    transpose_pos_kernel<<<dim3(Nc / 32, Dc / 32, Bc), dim3(32, 32), 0, stream>>>(
        x, cum_y, cum_x, lvl, src_f, src_bf, qpos_bf);
    // 2) merged sampling-offset + attn-weight projection; value projection
    gemm_bf16_kernel<<<dim3(3, BNc / 128), 256, 0, stream>>>(
        qpos_bf, soaw_wb, soaw_bias, soaw_f, nullptr, 324, Dc, 0, nullptr);
    gemm_bf16_kernel<<<dim3(3, BNc / 128), 256, 0, stream>>>(
        src_bf, vp_wb, vp_b, nullptr, value_bf, Dc, Dc, 0, qmask);
    // 3) softmax + pack attention weights
    softmax_pack_kernel<<<(BNc * Mc + 255) / 256, 256, 0, stream>>>(soaw_f, pack_f);
    // 4) deformable gather -> attn_bf (into qpos_bf region; qpos dead)
    deform_attn_kernel<<<(BNc * Mc) / 64, 256, 0, stream>>>(
        value_bf, soaw_f, pack_f, qpos_bf);
    // 5) output projection
    gemm_bf16_kernel<<<dim3(3, BNc / 128), 256, 0, stream>>>(
        qpos_bf, op_wb, op_b, proj_f, nullptr, Dc, Dc, 0, nullptr);
    // 6) q1 = LN(src + attnproj) — in place, bf16 copy to qpos_bf
    ln_residual_kernel<<<BNc, 128, 0, stream>>>(
        src_f, proj_f, ln1_g, ln1_b, src_f, qpos_bf);
    // 7) FFN
    gemm_bf16_kernel<<<dim3(9, BNc / 128), 256, 0, stream>>>(
        qpos_bf, w1_b, nullptr, nullptr, hbuf_bf, DFFc, Dc, 1, nullptr);
    gemm_bf16_kernel<<<dim3(3, BNc / 128), 256, 0, stream>>>(
        hbuf_bf, w2_b, nullptr, proj_f, nullptr, Dc, DFFc, 0, nullptr);
    // 8) q2 = LN(q1 + ffn2) — in place
    ln_residual_kernel<<<BNc, 128, 0, stream>>>(
        src_f, proj_f, ln2_g, ln2_b, src_f, nullptr);
    // 9) transpose to [B,D,H,W]
    transpose_out_kernel<<<dim3(Nc / 32, Dc / 32, Bc), dim3(32, 32), 0, stream>>>(
        src_f, out);
}